// Round 3
// baseline (174.395 us; speedup 1.0000x reference)
//
#include <hip/hip_runtime.h>
#include <math.h>

#define L_SEQ 4096
#define BSZ   4
#define DIM   1024
#define NDIM  16
#define BD    (BSZ*DIM)   /* 4096 == L_SEQ, so (bd,i) matrix is square */
#define TILE  64

// ---------------------------------------------------------------------------
// K1: transpose x (L, B*D) -> xT (B*D, L), staged into d_out.
// ---------------------------------------------------------------------------
__global__ __launch_bounds__(256) void k_transpose_in(const float* __restrict__ x,
                                                      float* __restrict__ xT) {
    __shared__ float tile[TILE][TILE + 1];
    const int I = blockIdx.x;          // i-tile
    const int J = blockIdx.y;          // bd-tile
    const int c  = threadIdx.x & 63;
    const int r0 = threadIdx.x >> 6;   // 0..3
    #pragma unroll
    for (int rr = 0; rr < TILE; rr += 4) {
        int r = r0 + rr;
        tile[r][c] = x[(size_t)(I * TILE + r) * BD + J * TILE + c];
    }
    __syncthreads();
    #pragma unroll
    for (int rr = 0; rr < TILE; rr += 4) {
        int r = r0 + rr;
        // xT[bd][i] = x[i][bd]
        xT[(size_t)(J * TILE + r) * L_SEQ + I * TILE + c] = tile[c][r];
    }
}

// ---------------------------------------------------------------------------
// K2: per-row bidirectional 16-state EMA scan, in place on the (bd, L) buffer.
// Block = 128 threads = 2 waves. Wave 0: forward (params row d). Wave 1:
// backward (params row D+d). Lane = chunk of 64 elements.
// ---------------------------------------------------------------------------
__global__ __launch_bounds__(128, 2) void k_scan(float* __restrict__ buf,
                                                 const float* __restrict__ delta,
                                                 const float* __restrict__ alpha,
                                                 const float* __restrict__ beta,
                                                 const float* __restrict__ gamma,
                                                 const float* __restrict__ omega) {
    __shared__ float y_s[64 * 65];   // element i at y_s[i + (i>>6)]  (pad-65)

    const int bd   = blockIdx.x;
    const int d    = bd & (DIM - 1);
    const int wave = threadIdx.x >> 6;   // 0 = fwd, 1 = bwd
    const int c    = threadIdx.x & 63;   // lane == chunk index
    const int d2   = (wave == 0) ? d : (DIM + d);

    // ---- per-(d2,n) params: lane n<16 computes, then broadcast via shfl ----
    float qv, wv;
    {
        const int n   = c & 15;
        const int idx = d2 * NDIM + n;
        const float dl = delta[idx], al = alpha[idx];
        const float bt = beta[idx],  gm = gamma[idx];
        const float p  = 1.0f / (1.0f + __expf(-dl));
        const float sa = 1.0f / (1.0f + __expf(-al));
        qv = 1.0f - p * sa;            // decay, in (0,1)
        wv = p * bt * gm * 0.25f;      // weight (scale = 1/sqrt(16))
    }
    float q[16], wt[16];
    #pragma unroll
    for (int n = 0; n < 16; ++n) {
        q[n]  = __shfl(qv, n, 64);
        wt[n] = __shfl(wv, n, 64);
    }

    // ---- load this lane's 64-element chunk into registers (bwd: reversed) ----
    float* row = buf + (size_t)bd * L_SEQ;
    float xr[64];
    if (wave == 0) {
        #pragma unroll
        for (int k = 0; k < 16; ++k) {
            float4 v = *(const float4*)(row + c * 64 + 4 * k);
            xr[4*k+0] = v.x; xr[4*k+1] = v.y; xr[4*k+2] = v.z; xr[4*k+3] = v.w;
        }
    } else {
        #pragma unroll
        for (int k = 0; k < 16; ++k) {
            float4 v = *(const float4*)(row + c * 64 + 60 - 4 * k);
            xr[4*k+0] = v.w; xr[4*k+1] = v.z; xr[4*k+2] = v.y; xr[4*k+3] = v.x;
        }
    }

    // ---- phase 1: per-chunk partial state (zero initial condition) ----
    float h[16];
    #pragma unroll
    for (int n = 0; n < 16; ++n) h[n] = 0.0f;
    #pragma unroll
    for (int j = 0; j < 64; ++j) {
        const float xv = xr[j];
        #pragma unroll
        for (int n = 0; n < 16; ++n) h[n] = fmaf(q[n], h[n], xv);
    }

    // ---- phase 2: Kogge-Stone scan across lanes; propagation factor q^64 ----
    float P[16];
    #pragma unroll
    for (int n = 0; n < 16; ++n) {
        float t = q[n];
        t *= t; t *= t; t *= t; t *= t; t *= t; t *= t;   // q^64
        P[n] = t;
    }
    #pragma unroll
    for (int s = 1; s < 64; s <<= 1) {
        #pragma unroll
        for (int n = 0; n < 16; ++n) {
            const float other = (wave == 0) ? __shfl_up(h[n], s, 64)
                                            : __shfl_down(h[n], s, 64);
            const bool valid  = (wave == 0) ? (c >= s) : (c + s < 64);
            if (valid) h[n] = fmaf(P[n], other, h[n]);
        }
        #pragma unroll
        for (int n = 0; n < 16; ++n) P[n] *= P[n];
    }
    float carry[16];
    #pragma unroll
    for (int n = 0; n < 16; ++n) {
        const float t = (wave == 0) ? __shfl_up(h[n], 1, 64)
                                    : __shfl_down(h[n], 1, 64);
        const bool edge = (wave == 0) ? (c == 0) : (c == 63);
        carry[n] = edge ? 0.0f : t;
    }

    // ---- phase 3: re-scan with correct carry, emit outputs ----
    const float omega_d = omega[d];
    if (wave == 0) {
        #pragma unroll
        for (int n = 0; n < 16; ++n) h[n] = carry[n];
        #pragma unroll
        for (int j = 0; j < 64; ++j) {
            const float xv = xr[j];
            float acc = 0.0f;
            #pragma unroll
            for (int n = 0; n < 16; ++n) {
                h[n] = fmaf(q[n], h[n], xv);
                acc  = fmaf(wt[n], h[n], acc);
            }
            y_s[c * 65 + j] = acc + xv * omega_d;   // + residual
        }
    }
    __syncthreads();
    if (wave == 1) {
        #pragma unroll
        for (int n = 0; n < 16; ++n) h[n] = carry[n];
        #pragma unroll
        for (int j = 0; j < 64; ++j) {
            const float xv = xr[j];                  // time 63-j within chunk
            float acc = 0.0f;
            #pragma unroll
            for (int n = 0; n < 16; ++n) {
                h[n] = fmaf(q[n], h[n], xv);
                acc  = fmaf(wt[n], h[n], acc);
            }
            y_s[c * 65 + (63 - j)] += acc;
        }
    }
    __syncthreads();

    // ---- write the finished row back (coalesced) ----
    for (int t = threadIdx.x; t < L_SEQ; t += 128) {
        row[t] = y_s[t + (t >> 6)];
    }
}

// ---------------------------------------------------------------------------
// K3: in-place transpose of the square (4096 x 4096) result: (bd,i) -> (i,bd).
// ---------------------------------------------------------------------------
__global__ __launch_bounds__(256) void k_transpose_inplace(float* __restrict__ M) {
    __shared__ float tA[TILE][TILE + 1];
    __shared__ float tB[TILE][TILE + 1];
    const int I = blockIdx.x;
    const int J = blockIdx.y;
    if (J < I) return;                  // each unordered pair handled once
    const int c  = threadIdx.x & 63;
    const int r0 = threadIdx.x >> 6;

    if (I == J) {
        #pragma unroll
        for (int rr = 0; rr < TILE; rr += 4) {
            int r = r0 + rr;
            tA[r][c] = M[(size_t)(I * TILE + r) * 4096 + I * TILE + c];
        }
        __syncthreads();
        #pragma unroll
        for (int rr = 0; rr < TILE; rr += 4) {
            int r = r0 + rr;
            M[(size_t)(I * TILE + r) * 4096 + I * TILE + c] = tA[c][r];
        }
    } else {
        #pragma unroll
        for (int rr = 0; rr < TILE; rr += 4) {
            int r = r0 + rr;
            tA[r][c] = M[(size_t)(I * TILE + r) * 4096 + J * TILE + c];
            tB[r][c] = M[(size_t)(J * TILE + r) * 4096 + I * TILE + c];
        }
        __syncthreads();
        #pragma unroll
        for (int rr = 0; rr < TILE; rr += 4) {
            int r = r0 + rr;
            M[(size_t)(J * TILE + r) * 4096 + I * TILE + c] = tA[c][r];
            M[(size_t)(I * TILE + r) * 4096 + J * TILE + c] = tB[c][r];
        }
    }
}

// ---------------------------------------------------------------------------
extern "C" void kernel_launch(void* const* d_in, const int* in_sizes, int n_in,
                              void* d_out, int out_size, void* d_ws, size_t ws_size,
                              hipStream_t stream) {
    const float* x     = (const float*)d_in[0];
    const float* delta = (const float*)d_in[1];
    const float* alpha = (const float*)d_in[2];
    const float* beta  = (const float*)d_in[3];
    const float* gamma = (const float*)d_in[4];
    const float* omega = (const float*)d_in[5];
    float* out = (float*)d_out;

    dim3 gT(BD / TILE, L_SEQ / TILE);   // 64 x 64 tiles
    k_transpose_in<<<gT, 256, 0, stream>>>(x, out);
    k_scan<<<BD, 128, 0, stream>>>(out, delta, alpha, beta, gamma, omega);
    k_transpose_inplace<<<gT, 256, 0, stream>>>(out);
}